// Round 1
// baseline (592.836 us; speedup 1.0000x reference)
//
#include <hip/hip_runtime.h>
#include <stdint.h>

#define THREADS 256
#define TILE_ROWS 256
#define DIM 9
#define NK 81
#define CB_ELEMS (NK * DIM * DIM) /* 6561 */
#define ENT_CAP 2048
#define CHUNK_PAD 17

// Zero the work-stealing counter each launch (graph-capture safe, same work every call).
__global__ void tp_init_counter(unsigned int* c) {
    if (threadIdx.x == 0 && blockIdx.x == 0) *c = 0u;
}

__global__ __launch_bounds__(THREADS, 3)
void tp_kernel(const float* __restrict__ in1, const float* __restrict__ in2,
               const float* __restrict__ cb, float* __restrict__ out,
               unsigned int* __restrict__ counter, int nrows, int ntiles) {
    __shared__ float s_in1[TILE_ROWS * DIM];          //  9.0 KB
    __shared__ float s_in2[TILE_ROWS * DIM];          //  9.0 KB
    __shared__ float s_chunk[TILE_ROWS * CHUNK_PAD];  // 17.0 KB (pad 17: odd stride, conflict-free)
    __shared__ float2 s_ent[ENT_CAP];                 // 16.0 KB  {packed(i,j) bits, value}
    __shared__ int s_cnt[NK];
    __shared__ int s_ptr[NK + 1];
    __shared__ int s_fill[NK];
    __shared__ unsigned int s_tile;

    const int tid = threadIdx.x;

    // ---- Phase A: runtime sparsity compaction of cb into CSR-by-k in LDS ----
    for (int k = tid; k < NK; k += THREADS) { s_cnt[k] = 0; s_fill[k] = 0; }
    __syncthreads();

    // Pass 1: count nonzeros per k (flat layout is k-major: f = k*81 + i*9 + j)
    for (int f = tid; f < CB_ELEMS; f += THREADS) {
        float v = cb[f];
        if (fabsf(v) > 1e-6f) {
            int k = f / NK;
            atomicAdd(&s_cnt[k], 1);
        }
    }
    __syncthreads();

    // Exclusive prefix scan over 81 counts, done by wave 0 via shfl scans.
    if (tid < 64) {
        int lane = tid;
        int incl = s_cnt[lane];
#pragma unroll
        for (int off = 1; off < 64; off <<= 1) {
            int u = __shfl_up(incl, off, 64);
            if (lane >= off) incl += u;
        }
        if (lane == 0) s_ptr[0] = 0;
        s_ptr[lane + 1] = incl;
        int tot64 = __shfl(incl, 63, 64);
        int incl2 = (lane < NK - 64) ? s_cnt[64 + lane] : 0;
#pragma unroll
        for (int off = 1; off < 64; off <<= 1) {
            int u = __shfl_up(incl2, off, 64);
            if (lane >= off) incl2 += u;
        }
        if (lane < NK - 64) s_ptr[64 + lane + 1] = tot64 + incl2;
    }
    __syncthreads();

    // Pass 2: scatter entries into their k-segment (order within k irrelevant for the sum).
    for (int f = tid; f < CB_ELEMS; f += THREADS) {
        float v = cb[f];
        if (fabsf(v) > 1e-6f) {
            int k = f / NK;
            int r = f - k * NK;
            int i = r / DIM;
            int j = r - i * DIM;
            int pos = s_ptr[k] + atomicAdd(&s_fill[k], 1);
            if (pos < ENT_CAP) {
                unsigned int pk = (unsigned int)i | ((unsigned int)j << 16);
                s_ent[pos] = make_float2(__uint_as_float(pk), v);
            }
        }
    }
    __syncthreads();

    // ---- Phase B: work-stolen row tiles ----
    const float* r1 = s_in1 + tid * DIM;
    const float* r2 = s_in2 + tid * DIM;

    for (;;) {
        if (tid == 0) s_tile = atomicAdd(counter, 1u);
        __syncthreads();
        unsigned int t = s_tile;
        if (t >= (unsigned int)ntiles) break;

        long rowbase = (long)t * TILE_ROWS;
        long remain = (long)nrows - rowbase;
        int rows = remain < TILE_ROWS ? (int)remain : TILE_ROWS;
        int nelts = rows * DIM;

        // Coalesced staging of input tiles.
        const float* g1 = in1 + rowbase * DIM;
        const float* g2 = in2 + rowbase * DIM;
        for (int x = tid; x < nelts; x += THREADS) s_in1[x] = g1[x];
        for (int x = tid; x < nelts; x += THREADS) s_in2[x] = g2[x];
        __syncthreads();

        float* gout = out + rowbase * NK;

        // k in 5 chunks: 16,16,16,16,17. Unrolled so chunk width is compile-time.
#pragma unroll
        for (int q = 0; q < 5; ++q) {
            const int k0 = q * 16;
            const int w = (q == 4) ? 17 : 16;
            int e = s_ptr[k0];
            for (int kk = 0; kk < w; ++kk) {
                int e1 = s_ptr[k0 + kk + 1];  // uniform broadcast read
                float acc = 0.0f;
                for (; e < e1; ++e) {
                    float2 en = s_ent[e];                       // uniform -> broadcast
                    unsigned int pk = __float_as_uint(en.x);
                    float a = r1[pk & 0xffffu];                 // stride-9: conflict-free
                    float b = r2[pk >> 16];
                    acc = fmaf(en.y, a * b, acc);
                }
                s_chunk[tid * CHUNK_PAD + kk] = acc;            // stride-17: conflict-free
            }
            __syncthreads();

            // Coalesced flush: 16 consecutive lanes cover one row's 16(17)-float segment.
            if (w == 16) {
                for (int x = tid; x < TILE_ROWS * 16; x += THREADS) {
                    int rr = x >> 4, cc = x & 15;
                    if (rr < rows)
                        gout[(long)rr * NK + k0 + cc] = s_chunk[rr * CHUNK_PAD + cc];
                }
            } else {
                for (int x = tid; x < TILE_ROWS * 17; x += THREADS) {
                    int rr = x / 17, cc = x - rr * 17;
                    if (rr < rows)
                        gout[(long)rr * NK + k0 + cc] = s_chunk[rr * CHUNK_PAD + cc];
                }
            }
            __syncthreads();
        }
    }
}

extern "C" void kernel_launch(void* const* d_in, const int* in_sizes, int n_in,
                              void* d_out, int out_size, void* d_ws, size_t ws_size,
                              hipStream_t stream) {
    const float* in1 = (const float*)d_in[0];
    const float* in2 = (const float*)d_in[1];
    const float* cb  = (const float*)d_in[2];
    float* out = (float*)d_out;
    unsigned int* counter = (unsigned int*)d_ws;

    int nrows = in_sizes[0] / DIM;                       // B = 1048576
    int ntiles = (nrows + TILE_ROWS - 1) / TILE_ROWS;    // 4096

    tp_init_counter<<<1, 64, 0, stream>>>(counter);
    // 768 blocks = 3 blocks/CU (LDS-limited) * 256 CUs; tiles are work-stolen so
    // occupancy shortfalls degrade gracefully instead of deadlocking/unbalancing.
    tp_kernel<<<768, THREADS, 0, stream>>>(in1, in2, cb, out, counter, nrows, ntiles);
}

// Round 2
// 481.017 us; speedup vs baseline: 1.2325x; 1.2325x over previous
//
#include <hip/hip_runtime.h>
#include <stdint.h>

#define THREADS 192          // 3 waves: wave w owns output-column tile [32w, 32w+32)
#define ROWS_PER_ITER 192
#define DIM 9
#define NK 81                // output cols
#define F 81                 // contraction dim (i*9+j), padded to 96
#define NCHUNK 6             // K-chunks of 16 along f
#define NGROUP 12            // 8-element (16 B) groups along f

typedef __attribute__((ext_vector_type(8))) short short8;   // 8 bf16 bit-patterns (4 VGPRs)
typedef __attribute__((ext_vector_type(16))) float f32x16;  // MFMA 32x32 accumulator

__device__ inline unsigned short f32_bf16(float x) {        // RNE fp32 -> bf16 bits
    unsigned u = __float_as_uint(x);
    u += 0x7FFFu + ((u >> 16) & 1u);
    return (unsigned short)(u >> 16);
}
__device__ inline float bf16_f32(unsigned short h) {
    return __uint_as_float(((unsigned)h) << 16);
}

__global__ __launch_bounds__(THREADS, 3)
void tp_mfma(const float* __restrict__ in1, const float* __restrict__ in2,
             const float* __restrict__ cb, float* __restrict__ out,
             int nrows, int niter) {
    // P staged chunk-major: [group g=0..11][row 0..191][8 bf16 = 16 B].
    // Both ds_write_b128 (lane=row) and A-frag ds_read_b128 are contiguous -> conflict-free.
    __shared__ __attribute__((aligned(16))) unsigned short s_p[NGROUP * ROWS_PER_ITER * 8]; // 36 KB

    const int tid  = threadIdx.x;
    const int lane = tid & 63;
    const int wave = tid >> 6;       // 0..2 -> column tile
    const int l31  = lane & 31;
    const int h    = lane >> 5;
    const int kcol = 32 * wave + l31;  // this lane's output column (B n-index / C col)

    // ---- Stationary B (= W) fragments, hi+lo split, in registers ----
    // B[kf][n]: n = l31, kf = h*8 + j within chunk c; f = c*16 + kf; W[f][k] = cb[k*81 + f]
    short8 Bhi[NCHUNK], Blo[NCHUNK];
    for (int c = 0; c < NCHUNK; ++c) {
        union { short8 v; unsigned short u[8]; } bh, bl;
        for (int j = 0; j < 8; ++j) {
            int f = c * 16 + h * 8 + j;
            float v = 0.0f;
            if (f < F && kcol < NK) v = cb[kcol * F + f];
            unsigned short hi = f32_bf16(v);
            bh.u[j] = (unsigned short)hi;
            bl.u[j] = f32_bf16(v - bf16_f32(hi));
        }
        Bhi[c] = bh.v; Blo[c] = bl.v;
    }

    for (int iter = blockIdx.x; iter < niter; iter += gridDim.x) {
        const long rowbase = (long)iter * ROWS_PER_ITER;
        const long row = rowbase + tid;

        __syncthreads();  // previous iteration's A-frag readers must finish before overwrite

        // ---- Phase 1: per-thread row -> P[f] = a[i]*b[j], bf16, to LDS ----
        float a[DIM], b[DIM];
        if (row < nrows) {
            const float* p1 = in1 + row * DIM;
            const float* p2 = in2 + row * DIM;
#pragma unroll
            for (int i = 0; i < DIM; ++i) { a[i] = p1[i]; b[i] = p2[i]; }
        } else {
#pragma unroll
            for (int i = 0; i < DIM; ++i) { a[i] = 0.0f; b[i] = 0.0f; }
        }
#pragma unroll
        for (int g = 0; g < NGROUP; ++g) {
            unsigned int d[4];
#pragma unroll
            for (int q = 0; q < 4; ++q) {
                const int f0 = g * 8 + 2 * q, f1 = f0 + 1;
                unsigned short h0 = (f0 < F) ? f32_bf16(a[f0 / DIM] * b[f0 % DIM]) : (unsigned short)0;
                unsigned short h1 = (f1 < F) ? f32_bf16(a[f1 / DIM] * b[f1 % DIM]) : (unsigned short)0;
                d[q] = (unsigned)h0 | ((unsigned)h1 << 16);
            }
            ((uint4*)s_p)[g * ROWS_PER_ITER + tid] = make_uint4(d[0], d[1], d[2], d[3]);
        }
        __syncthreads();

        // ---- Phase 2: MFMA. Wave w computes rows [0,192) x cols [32w, 32w+32) ----
#pragma unroll
        for (int st = 0; st < 6; ++st) {
            const int m0 = st * 32;
            f32x16 acc = {0.f,0.f,0.f,0.f, 0.f,0.f,0.f,0.f, 0.f,0.f,0.f,0.f, 0.f,0.f,0.f,0.f};
#pragma unroll
            for (int c = 0; c < NCHUNK; ++c) {
                const int cidx = c * 2 + h;  // A[k = h*8+j] lives in group cidx
                short8 A = ((const short8*)s_p)[cidx * ROWS_PER_ITER + m0 + l31];
                acc = __builtin_amdgcn_mfma_f32_32x32x16_bf16(A, Bhi[c], acc, 0, 0, 0);
                acc = __builtin_amdgcn_mfma_f32_32x32x16_bf16(A, Blo[c], acc, 0, 0, 0);
            }
            // C/D: col = lane&31, row = (reg&3) + 8*(reg>>2) + 4*(lane>>5)  [m74/m101]
            if (kcol < NK) {
#pragma unroll
                for (int r = 0; r < 16; ++r) {
                    const int mrow = m0 + (r & 3) + 8 * (r >> 2) + 4 * h;
                    const long grow = rowbase + mrow;
                    if (grow < nrows) out[grow * NK + kcol] = acc[r];
                }
            }
        }
    }
}

extern "C" void kernel_launch(void* const* d_in, const int* in_sizes, int n_in,
                              void* d_out, int out_size, void* d_ws, size_t ws_size,
                              hipStream_t stream) {
    const float* in1 = (const float*)d_in[0];
    const float* in2 = (const float*)d_in[1];
    const float* cb  = (const float*)d_in[2];
    float* out = (float*)d_out;

    int nrows = in_sizes[0] / DIM;                              // 1048576
    int niter = (nrows + ROWS_PER_ITER - 1) / ROWS_PER_ITER;    // 5462

    // 1024 blocks = 4 blocks/CU (LDS: 36 KB -> 4/CU; launch_bounds(192,3) = 3 waves/EU)
    tp_mfma<<<1024, THREADS, 0, stream>>>(in1, in2, cb, out, nrows, niter);
}